// Round 3
// baseline (336.571 us; speedup 1.0000x reference)
//
#include <hip/hip_runtime.h>
#include <hip/hip_bf16.h>

#define BSZ 8192
#define DIM 128
#define LOG2E 1.4426950408889634f

typedef __attribute__((ext_vector_type(8))) short bf16x8;
typedef __attribute__((ext_vector_type(4))) float f32x4;

__device__ __forceinline__ ushort f32_to_bf16(float f) {
    unsigned u = __float_as_uint(f);
    u += 0x7FFF + ((u >> 16) & 1);   // round-to-nearest-even
    return (ushort)(u >> 16);
}

// K1: per-row sum of squares (prescaled by log2e/512) + bf16 conversion of x
// into a BLOCKED fragment layout: xb[((g*4+kk)*64 + lane)*8 + e] =
// bf16(x[g*16 + (lane&15)][kk*32 + (lane>>4)*8 + e]).  One MFMA fragment load
// = 64 lanes x 16 B contiguous = one coalesced 1 KB transaction.
__global__ __launch_bounds__(256) void prep_kernel(const float* __restrict__ x,
                                                   ushort* __restrict__ xb,
                                                   float* __restrict__ sq2) {
    const int wid  = threadIdx.x >> 6;
    const int lane = threadIdx.x & 63;
    const int g    = blockIdx.x * 4 + wid;   // 16-row group, 0..511
    const int fr   = lane & 15;
    const int kg   = lane >> 4;
    const int row  = g * 16 + fr;

    float s = 0.f;
    #pragma unroll
    for (int kk = 0; kk < 4; ++kk) {
        const float* p = x + (size_t)row * DIM + kk * 32 + kg * 8;
        const float4 v0 = *reinterpret_cast<const float4*>(p);
        const float4 v1 = *reinterpret_cast<const float4*>(p + 4);
        s += v0.x * v0.x + v0.y * v0.y + v0.z * v0.z + v0.w * v0.w;
        s += v1.x * v1.x + v1.y * v1.y + v1.z * v1.z + v1.w * v1.w;
        bf16x8 b;
        b[0] = (short)f32_to_bf16(v0.x); b[1] = (short)f32_to_bf16(v0.y);
        b[2] = (short)f32_to_bf16(v0.z); b[3] = (short)f32_to_bf16(v0.w);
        b[4] = (short)f32_to_bf16(v1.x); b[5] = (short)f32_to_bf16(v1.y);
        b[6] = (short)f32_to_bf16(v1.z); b[7] = (short)f32_to_bf16(v1.w);
        *reinterpret_cast<bf16x8*>(xb + ((size_t)(g * 4 + kk) * 64 + lane) * 8) = b;
    }
    s += __shfl_xor(s, 16);
    s += __shfl_xor(s, 32);
    if (lane < 16) sq2[row] = s * (LOG2E / 512.f);
}

// Shared 128x128-tile MFMA compute: acc[mi][ni] over K=128.
__device__ __forceinline__ void compute_tile(const ushort* __restrict__ xb,
                                             int ga, int gb, int lane,
                                             f32x4 (&acc)[4][4]) {
    #pragma unroll
    for (int mi = 0; mi < 4; ++mi)
        #pragma unroll
        for (int ni = 0; ni < 4; ++ni)
            acc[mi][ni] = (f32x4){0.f, 0.f, 0.f, 0.f};
    #pragma unroll
    for (int kk = 0; kk < 4; ++kk) {
        bf16x8 a[4], b[4];
        #pragma unroll
        for (int mi = 0; mi < 4; ++mi)
            a[mi] = *reinterpret_cast<const bf16x8*>(
                xb + ((size_t)((ga + mi) * 4 + kk) * 64 + lane) * 8);
        #pragma unroll
        for (int ni = 0; ni < 4; ++ni)
            b[ni] = *reinterpret_cast<const bf16x8*>(
                xb + ((size_t)((gb + ni) * 4 + kk) * 64 + lane) * 8);
        #pragma unroll
        for (int mi = 0; mi < 4; ++mi)
            #pragma unroll
            for (int ni = 0; ni < 4; ++ni)
                acc[mi][ni] = __builtin_amdgcn_mfma_f32_16x16x32_bf16(a[mi], b[ni], acc[mi][ni], 0, 0, 0);
    }
}

// Phase 0 (symmetric): upper-triangle tiles (by <= bx). Accumulate tile column
// sums (-> colsum of bx-block) and tile row sums (-> colsum of by-block, via
// symmetry; skipped on diagonal). No atomics to global: each tile writes its
// 128(+128) partials to part[64][8192], every slot written exactly once.
__global__ __launch_bounds__(256) void rbf_colsum(const ushort* __restrict__ xb,
                                                  const float* __restrict__ sq2,
                                                  float* __restrict__ part) {
    const int t = blockIdx.x;
    int bx = (int)((sqrtf(8.f * t + 1.f) - 1.f) * 0.5f);
    while ((bx + 1) * (bx + 2) / 2 <= t) ++bx;
    while (bx * (bx + 1) / 2 > t) --bx;
    const int by = t - bx * (bx + 1) / 2;   // by <= bx

    const int lane = threadIdx.x & 63;
    const int wid  = threadIdx.x >> 6;
    const int fr   = lane & 15;
    const int kg   = lane >> 4;
    const int row0 = by * 128 + (wid >> 1) * 64;
    const int col0 = bx * 128 + (wid & 1) * 64;

    f32x4 acc[4][4];
    compute_tile(xb, row0 >> 4, col0 >> 4, lane, acc);

    float sq2r[4][4];
    #pragma unroll
    for (int mi = 0; mi < 4; ++mi) {
        const f32x4 v = *reinterpret_cast<const f32x4*>(sq2 + row0 + mi * 16 + kg * 4);
        #pragma unroll
        for (int r = 0; r < 4; ++r) sq2r[mi][r] = v[r];
    }
    float sq2c[4];
    #pragma unroll
    for (int ni = 0; ni < 4; ++ni) sq2c[ni] = sq2[col0 + ni * 16 + fr];

    const float C2 = LOG2E / 256.f;   // 2 * log2e / 512
    float csum[4] = {0.f, 0.f, 0.f, 0.f};
    float rsum[4][4];
    #pragma unroll
    for (int mi = 0; mi < 4; ++mi)
        #pragma unroll
        for (int r = 0; r < 4; ++r) rsum[mi][r] = 0.f;

    #pragma unroll
    for (int mi = 0; mi < 4; ++mi)
        #pragma unroll
        for (int ni = 0; ni < 4; ++ni)
            #pragma unroll
            for (int r = 0; r < 4; ++r) {
                float tv = fminf(fmaf(acc[mi][ni][r], C2, -sq2r[mi][r]) - sq2c[ni], 0.f);
                float e = __builtin_amdgcn_exp2f(tv);
                csum[ni] += e;
                rsum[mi][r] += e;
            }

    // col sums: reduce over kg (lane bits 4,5)
    #pragma unroll
    for (int ni = 0; ni < 4; ++ni) {
        csum[ni] += __shfl_xor(csum[ni], 16);
        csum[ni] += __shfl_xor(csum[ni], 32);
    }
    // row sums: reduce over fr (lane bits 0..3)
    #pragma unroll
    for (int mi = 0; mi < 4; ++mi)
        #pragma unroll
        for (int r = 0; r < 4; ++r) {
            float v = rsum[mi][r];
            v += __shfl_xor(v, 1);
            v += __shfl_xor(v, 2);
            v += __shfl_xor(v, 4);
            v += __shfl_xor(v, 8);
            rsum[mi][r] = v;
        }

    __shared__ float cs[128], rs[128];
    if (threadIdx.x < 128) cs[threadIdx.x] = 0.f;
    else rs[threadIdx.x - 128] = 0.f;
    __syncthreads();
    if (lane < 16) {
        #pragma unroll
        for (int ni = 0; ni < 4; ++ni)
            atomicAdd(&cs[(wid & 1) * 64 + ni * 16 + fr], csum[ni]);
    }
    if (fr == 0) {
        #pragma unroll
        for (int mi = 0; mi < 4; ++mi)
            #pragma unroll
            for (int r = 0; r < 4; ++r)
                atomicAdd(&rs[(wid >> 1) * 64 + mi * 16 + kg * 4 + r], rsum[mi][r]);
    }
    __syncthreads();
    if (threadIdx.x < 128)
        part[(size_t)by * BSZ + bx * 128 + threadIdx.x] = cs[threadIdx.x];
    else if (by < bx)
        part[(size_t)bx * BSZ + by * 128 + (threadIdx.x - 128)] = rs[threadIdx.x - 128];
}

// Deterministic reduction: colsum[j] = sum_a part[a][j].
__global__ __launch_bounds__(256) void reduce_colsum(const float* __restrict__ part,
                                                     float* __restrict__ colsum) {
    const int j = blockIdx.x * 256 + threadIdx.x;
    float s = 0.f;
    #pragma unroll
    for (int a = 0; a < 64; ++a) s += part[(size_t)a * BSZ + j];
    colsum[j] = s;
}

// Phase 1: recompute kernel values, normalize, stream out (full 4096 tiles).
__global__ __launch_bounds__(256) void rbf_write(const ushort* __restrict__ xb,
                                                 const float* __restrict__ sq2,
                                                 const float* __restrict__ colsum,
                                                 float* __restrict__ out) {
    const int lane = threadIdx.x & 63;
    const int wid  = threadIdx.x >> 6;
    const int fr   = lane & 15;
    const int kg   = lane >> 4;
    const int bx = blockIdx.x & 63;
    const int by = blockIdx.x >> 6;
    const int row0 = by * 128 + (wid >> 1) * 64;
    const int col0 = bx * 128 + (wid & 1) * 64;

    f32x4 acc[4][4];
    compute_tile(xb, row0 >> 4, col0 >> 4, lane, acc);

    float sq2r[4][4], dsr[4][4];
    #pragma unroll
    for (int mi = 0; mi < 4; ++mi) {
        const f32x4 v = *reinterpret_cast<const f32x4*>(sq2 + row0 + mi * 16 + kg * 4);
        const f32x4 c = *reinterpret_cast<const f32x4*>(colsum + row0 + mi * 16 + kg * 4);
        #pragma unroll
        for (int r = 0; r < 4; ++r) { sq2r[mi][r] = v[r]; dsr[mi][r] = rsqrtf(c[r]); }
    }
    float sq2c[4], dsc[4];
    #pragma unroll
    for (int ni = 0; ni < 4; ++ni) {
        sq2c[ni] = sq2[col0 + ni * 16 + fr];
        dsc[ni]  = rsqrtf(colsum[col0 + ni * 16 + fr]);
    }

    const float C2 = LOG2E / 256.f;
    #pragma unroll
    for (int mi = 0; mi < 4; ++mi)
        #pragma unroll
        for (int ni = 0; ni < 4; ++ni) {
            const float sc = dsc[ni];
            #pragma unroll
            for (int r = 0; r < 4; ++r) {
                float tv = fminf(fmaf(acc[mi][ni][r], C2, -sq2r[mi][r]) - sq2c[ni], 0.f);
                float e = __builtin_amdgcn_exp2f(tv);
                const int row = row0 + mi * 16 + kg * 4 + r;
                const int col = col0 + ni * 16 + fr;
                __builtin_nontemporal_store(e * dsr[mi][r] * sc,
                                            &out[(size_t)row * BSZ + col]);
            }
        }
}

extern "C" void kernel_launch(void* const* d_in, const int* in_sizes, int n_in,
                              void* d_out, int out_size, void* d_ws, size_t ws_size,
                              hipStream_t stream) {
    const float* x = (const float*)d_in[0];
    float* out = (float*)d_out;

    ushort* xb    = (ushort*)d_ws;                                  // 2 MiB blocked bf16
    float* sq2    = (float*)((char*)d_ws + (size_t)BSZ * DIM * 2);  // 32 KiB
    float* colsum = sq2 + BSZ;                                      // 32 KiB
    float* part   = colsum + BSZ;                                   // 64*8192*4 = 2 MiB

    prep_kernel<<<512 / 4, 256, 0, stream>>>(x, xb, sq2);
    rbf_colsum<<<2080, 256, 0, stream>>>(xb, sq2, part);
    reduce_colsum<<<BSZ / 256, 256, 0, stream>>>(part, colsum);
    rbf_write<<<64 * 64, 256, 0, stream>>>(xb, sq2, colsum, out);
}

// Round 8
// 316.276 us; speedup vs baseline: 1.0642x; 1.0642x over previous
//
#include <hip/hip_runtime.h>
#include <hip/hip_bf16.h>

#define BSZ 8192
#define DIM 128
#define LOG2E 1.4426950408889634f
#define C2 (LOG2E / 256.f)

typedef __attribute__((ext_vector_type(8))) short bf16x8;
typedef __attribute__((ext_vector_type(4))) float f32x4;

__device__ __forceinline__ ushort f32_to_bf16(float f) {
    unsigned u = __float_as_uint(f);
    u += 0x7FFF + ((u >> 16) & 1);   // round-to-nearest-even
    return (ushort)(u >> 16);
}

// K1: per-row sum of squares (prescaled by log2e/512) + bf16 conversion of x
// into a BLOCKED fragment layout: xb[((g*4+kk)*64 + lane)*8 + e] =
// bf16(x[g*16 + (lane&15)][kk*32 + (lane>>4)*8 + e]).  One MFMA fragment load
// = 64 lanes x 16 B contiguous = one coalesced 1 KB transaction.
__global__ __launch_bounds__(256) void prep_kernel(const float* __restrict__ x,
                                                   ushort* __restrict__ xb,
                                                   float* __restrict__ sq2) {
    const int wid  = threadIdx.x >> 6;
    const int lane = threadIdx.x & 63;
    const int g    = blockIdx.x * 4 + wid;   // 16-row group, 0..511
    const int fr   = lane & 15;
    const int kg   = lane >> 4;
    const int row  = g * 16 + fr;

    float s = 0.f;
    #pragma unroll
    for (int kk = 0; kk < 4; ++kk) {
        const float* p = x + (size_t)row * DIM + kk * 32 + kg * 8;
        const float4 v0 = *reinterpret_cast<const float4*>(p);
        const float4 v1 = *reinterpret_cast<const float4*>(p + 4);
        s += v0.x * v0.x + v0.y * v0.y + v0.z * v0.z + v0.w * v0.w;
        s += v1.x * v1.x + v1.y * v1.y + v1.z * v1.z + v1.w * v1.w;
        bf16x8 b;
        b[0] = (short)f32_to_bf16(v0.x); b[1] = (short)f32_to_bf16(v0.y);
        b[2] = (short)f32_to_bf16(v0.z); b[3] = (short)f32_to_bf16(v0.w);
        b[4] = (short)f32_to_bf16(v1.x); b[5] = (short)f32_to_bf16(v1.y);
        b[6] = (short)f32_to_bf16(v1.z); b[7] = (short)f32_to_bf16(v1.w);
        *reinterpret_cast<bf16x8*>(xb + ((size_t)(g * 4 + kk) * 64 + lane) * 8) = b;
    }
    s += __shfl_xor(s, 16);
    s += __shfl_xor(s, 32);
    if (lane < 16) sq2[row] = s * (LOG2E / 512.f);
}

// 128x128-tile MFMA compute over K=128 on blocked xb.
// m89 C/D layout: A-operand index -> (lane>>4)*4 + reg, B-operand index -> lane&15.
__device__ __forceinline__ void compute_tile(const ushort* __restrict__ xb,
                                             int ga, int gb, int lane,
                                             f32x4 (&acc)[4][4]) {
    #pragma unroll
    for (int ai = 0; ai < 4; ++ai)
        #pragma unroll
        for (int bi = 0; bi < 4; ++bi)
            acc[ai][bi] = (f32x4){0.f, 0.f, 0.f, 0.f};
    #pragma unroll
    for (int kk = 0; kk < 4; ++kk) {
        bf16x8 a[4], b[4];
        #pragma unroll
        for (int ai = 0; ai < 4; ++ai)
            a[ai] = *reinterpret_cast<const bf16x8*>(
                xb + ((size_t)((ga + ai) * 4 + kk) * 64 + lane) * 8);
        #pragma unroll
        for (int bi = 0; bi < 4; ++bi)
            b[bi] = *reinterpret_cast<const bf16x8*>(
                xb + ((size_t)((gb + bi) * 4 + kk) * 64 + lane) * 8);
        #pragma unroll
        for (int ai = 0; ai < 4; ++ai)
            #pragma unroll
            for (int bi = 0; bi < 4; ++bi)
                acc[ai][bi] = __builtin_amdgcn_mfma_f32_16x16x32_bf16(a[ai], b[bi], acc[ai][bi], 0, 0, 0);
    }
}

// Phase 0 (R2-proven structure): full 4096 tiles, column sums via wave reduce +
// global atomicAdd. a = rows, b = cols.
__global__ __launch_bounds__(256) void rbf_colsum(const ushort* __restrict__ xb,
                                                  const float* __restrict__ sq2,
                                                  float* __restrict__ colsum) {
    const int lane = threadIdx.x & 63;
    const int wid  = threadIdx.x >> 6;
    const int fr   = lane & 15;
    const int kg   = lane >> 4;
    const int bx = blockIdx.x & 63;
    const int by = blockIdx.x >> 6;
    const int row0 = by * 128 + (wid >> 1) * 64;
    const int col0 = bx * 128 + (wid & 1) * 64;

    f32x4 acc[4][4];
    compute_tile(xb, row0 >> 4, col0 >> 4, lane, acc);

    float sq2r[4][4];
    #pragma unroll
    for (int mi = 0; mi < 4; ++mi) {
        const f32x4 v = *reinterpret_cast<const f32x4*>(sq2 + row0 + mi * 16 + kg * 4);
        #pragma unroll
        for (int r = 0; r < 4; ++r) sq2r[mi][r] = v[r];
    }
    float sq2c[4];
    #pragma unroll
    for (int ni = 0; ni < 4; ++ni) sq2c[ni] = sq2[col0 + ni * 16 + fr];

    float csum[4] = {0.f, 0.f, 0.f, 0.f};
    #pragma unroll
    for (int mi = 0; mi < 4; ++mi)
        #pragma unroll
        for (int ni = 0; ni < 4; ++ni)
            #pragma unroll
            for (int r = 0; r < 4; ++r) {
                float tv = fminf(fmaf(acc[mi][ni][r], C2, -sq2r[mi][r]) - sq2c[ni], 0.f);
                csum[ni] += __builtin_amdgcn_exp2f(tv);
            }
    #pragma unroll
    for (int ni = 0; ni < 4; ++ni) {
        csum[ni] += __shfl_xor(csum[ni], 16);
        csum[ni] += __shfl_xor(csum[ni], 32);
    }
    if (lane < 16) {
        #pragma unroll
        for (int ni = 0; ni < 4; ++ni)
            atomicAdd(&colsum[col0 + ni * 16 + fr], csum[ni]);
    }
}

// Phase 1: SWAPPED operands (a = col-fragments, b = row-fragments).  By dot
// symmetry acc[ci][ri] reg r = K[row0+ri*16+fr][col0+ci*16+kg*4+r], so each
// lane's f32x4 is 4 consecutive columns of one row -> aligned dwordx4 stores,
// 4x fewer store instructions; the ci loop emits 4 adjacent 64B segments per
// row for TCC write combining.
__global__ __launch_bounds__(256) void rbf_write(const ushort* __restrict__ xb,
                                                 const float* __restrict__ sq2,
                                                 const float* __restrict__ colsum,
                                                 float* __restrict__ out) {
    const int lane = threadIdx.x & 63;
    const int wid  = threadIdx.x >> 6;
    const int fr   = lane & 15;
    const int kg   = lane >> 4;
    const int bx = blockIdx.x & 63;
    const int by = blockIdx.x >> 6;
    const int row0 = by * 128 + (wid >> 1) * 64;
    const int col0 = bx * 128 + (wid & 1) * 64;

    f32x4 acc[4][4];
    compute_tile(xb, col0 >> 4, row0 >> 4, lane, acc);  // a=cols, b=rows

    float sq2r[4], dsr[4];
    #pragma unroll
    for (int ri = 0; ri < 4; ++ri) {
        const int R = row0 + ri * 16 + fr;
        sq2r[ri] = sq2[R];
        dsr[ri]  = rsqrtf(colsum[R]);
    }
    f32x4 sq2c[4], dsc[4];
    #pragma unroll
    for (int ci = 0; ci < 4; ++ci) {
        sq2c[ci] = *reinterpret_cast<const f32x4*>(sq2 + col0 + ci * 16 + kg * 4);
        const f32x4 c = *reinterpret_cast<const f32x4*>(colsum + col0 + ci * 16 + kg * 4);
        f32x4 d;
        #pragma unroll
        for (int r = 0; r < 4; ++r) d[r] = rsqrtf(c[r]);
        dsc[ci] = d;
    }

    #pragma unroll
    for (int ri = 0; ri < 4; ++ri) {
        const int R = row0 + ri * 16 + fr;
        float* rowp = out + (size_t)R * BSZ + col0 + kg * 4;
        #pragma unroll
        for (int ci = 0; ci < 4; ++ci) {
            f32x4 v;
            #pragma unroll
            for (int r = 0; r < 4; ++r) {
                float tv = fminf(fmaf(acc[ci][ri][r], C2, -sq2r[ri]) - sq2c[ci][r], 0.f);
                v[r] = __builtin_amdgcn_exp2f(tv) * dsr[ri] * dsc[ci][r];
            }
            __builtin_nontemporal_store(v, reinterpret_cast<f32x4*>(rowp + ci * 16));
        }
    }
}

extern "C" void kernel_launch(void* const* d_in, const int* in_sizes, int n_in,
                              void* d_out, int out_size, void* d_ws, size_t ws_size,
                              hipStream_t stream) {
    const float* x = (const float*)d_in[0];
    float* out = (float*)d_out;

    ushort* xb    = (ushort*)d_ws;                                  // 2 MiB blocked bf16
    float* sq2    = (float*)((char*)d_ws + (size_t)BSZ * DIM * 2);  // 32 KiB
    float* colsum = sq2 + BSZ;                                      // 32 KiB

    hipMemsetAsync(colsum, 0, BSZ * sizeof(float), stream);
    prep_kernel<<<512 / 4, 256, 0, stream>>>(x, xb, sq2);
    rbf_colsum<<<64 * 64, 256, 0, stream>>>(xb, sq2, colsum);
    rbf_write<<<64 * 64, 256, 0, stream>>>(xb, sq2, colsum, out);
}